// Round 2
// baseline (7840.971 us; speedup 1.0000x reference)
//
#include <hip/hip_runtime.h>
#include <math.h>

#define N 4096
#define DIM 64
#define MAX_ITER 50
#define EPS 0.1f
#define INV_EPS 10.0f
#define THRESH 0.1f

// persistent-kernel geometry: 2048 blocks x 256 threads, 8 blocks/CU co-resident
// (launch_bounds(256,8) -> VGPR<=64 -> 32 waves/CU; LDS 512B; co-residency by
// capacity: 8 blocks/CU x 256 CUs == grid, so the grid barrier cannot deadlock)
#define NBLK 2048
#define RPB 2              // rows per block
#define NGRP 32            // barrier groups
#define GRP_SZ (NBLK / NGRP)

// ws layout (floats). ~35 KB total.
#define WS_ERR  (2 * N)            // err[MAX_ITER]
#define WS_COST (2 * N + 50)       // cost accumulator
#define WS_GEN  (2 * N + 64)       // barrier generation (own cache line)
#define WS_ROOT (2 * N + 80)       // barrier root counter (own cache line)
#define WS_L1   (2 * N + 96)       // 32 group counters, 64B stride
#define WS_TOTAL (2 * N + 96 + NGRP * 16)

// ---------------- init: zero u, v, err, cost, barrier counters ----------------
__global__ void init_ws(float* __restrict__ ws) {
    int i = blockIdx.x * 256 + threadIdx.x;
    if (i < WS_TOTAL) ws[i] = 0.0f;
}

// ---------------- build D[i][j] = sum_d (A[i][d]-B[j][d])^2 ----------------
// grid (64,64), block 256. 64x64 tile per block, 4x4 micro-tile per thread.
__global__ __launch_bounds__(256) void build_dist(const float* __restrict__ A,
                                                  const float* __restrict__ B,
                                                  float* __restrict__ Dst) {
    __shared__ float As[64][68];
    __shared__ float Bs[64][68];
    const int i0 = blockIdx.y << 6, j0 = blockIdx.x << 6;
    const int t = threadIdx.x;
    const float* Ag = A + (size_t)i0 * DIM;
    const float* Bg = B + (size_t)j0 * DIM;
    for (int k = t; k < 4096; k += 256) {
        As[k >> 6][k & 63] = Ag[k];
        Bs[k >> 6][k & 63] = Bg[k];
    }
    __syncthreads();
    const int ty = t >> 4, tx = t & 15;
    float acc[4][4] = {{0.f}};
    for (int d = 0; d < DIM; d += 4) {
        float4 av[4], bv[4];
#pragma unroll
        for (int a = 0; a < 4; ++a) av[a] = *(const float4*)&As[ty + 16 * a][d];
#pragma unroll
        for (int b = 0; b < 4; ++b) bv[b] = *(const float4*)&Bs[tx + 16 * b][d];
#pragma unroll
        for (int a = 0; a < 4; ++a)
#pragma unroll
            for (int b = 0; b < 4; ++b) {
                float d0 = av[a].x - bv[b].x;
                float d1 = av[a].y - bv[b].y;
                float d2 = av[a].z - bv[b].z;
                float d3 = av[a].w - bv[b].w;
                acc[a][b] = fmaf(d0, d0, acc[a][b]);
                acc[a][b] = fmaf(d1, d1, acc[a][b]);
                acc[a][b] = fmaf(d2, d2, acc[a][b]);
                acc[a][b] = fmaf(d3, d3, acc[a][b]);
            }
    }
#pragma unroll
    for (int a = 0; a < 4; ++a) {
        int i = i0 + ty + 16 * a;
        float* drow = Dst + (size_t)i * N + j0;
#pragma unroll
        for (int b = 0; b < 4; ++b) drow[tx + 16 * b] = acc[a][b];
    }
}

// ---------------- software grid barrier (two-level, monotone, no resets) -------
__device__ __forceinline__ void grid_sync(float* ws, int b) {
    __syncthreads();  // drains this block's stores before arrival
    if (threadIdx.x == 0) {
        unsigned* gen  = (unsigned*)(ws + WS_GEN);
        unsigned* root = (unsigned*)(ws + WS_ROOT);
        unsigned* l1   = (unsigned*)(ws + WS_L1) + (size_t)(b & (NGRP - 1)) * 16;
        unsigned old1 = __hip_atomic_fetch_add(l1, 1u, __ATOMIC_ACQ_REL,
                                               __HIP_MEMORY_SCOPE_AGENT);
        unsigned target = old1 / GRP_SZ + 1u;      // barrier index + 1
        if ((old1 % GRP_SZ) == GRP_SZ - 1u) {      // last of group -> arrive at root
            unsigned old0 = __hip_atomic_fetch_add(root, 1u, __ATOMIC_ACQ_REL,
                                                   __HIP_MEMORY_SCOPE_AGENT);
            if ((old0 % NGRP) == NGRP - 1u)        // last group -> release new gen
                __hip_atomic_store(gen, old0 / NGRP + 1u, __ATOMIC_RELEASE,
                                   __HIP_MEMORY_SCOPE_AGENT);
        }
        while (__hip_atomic_load(gen, __ATOMIC_RELAXED, __HIP_MEMORY_SCOPE_AGENT) <
               target)
            __builtin_amdgcn_s_sleep(16);
        __builtin_amdgcn_fence(__ATOMIC_ACQUIRE, "agent");  // u/v/err visibility
    }
    __syncthreads();
}

// ---------------- one Sinkhorn half-step, 2 rows per block, SINGLE PASS -------
// Payload held live across both passes: 8 C-float4 + 4 V-float4 = 48 VGPRs,
// fits the 64-VGPR budget of launch_bounds(256,8) -> no compiler reload of C.
// new_i = target - max_j(o_j - M_ij) - EPS*log(sum_j exp((d_j - dmax)*INV_EPS))
template <bool WRITE_ERR>
__device__ __forceinline__ void half_step(const float* __restrict__ Mtx,
                                          const float* __restrict__ other,
                                          float* __restrict__ mine,
                                          float* __restrict__ errslot, int r0,
                                          int t, float target, float* red) {
    const float4* __restrict__ row0 = (const float4*)(Mtx + (size_t)r0 * N);
    const float4* __restrict__ row1 = (const float4*)(Mtx + (size_t)(r0 + 1) * N);
    const float4* __restrict__ vv = (const float4*)other;
    float4 C0[4], C1[4], V[4];
#pragma unroll
    for (int k = 0; k < 4; ++k) {
        const int f = t + 256 * k;  // float4 index 0..1023, lane-consecutive
        C0[k] = row0[f];
        C1[k] = row1[f];
        V[k] = vv[f];
    }
    float m0 = -1e30f, m1 = -1e30f;
#pragma unroll
    for (int k = 0; k < 4; ++k) {
        m0 = fmaxf(m0, fmaxf(fmaxf(V[k].x - C0[k].x, V[k].y - C0[k].y),
                             fmaxf(V[k].z - C0[k].z, V[k].w - C0[k].w)));
        m1 = fmaxf(m1, fmaxf(fmaxf(V[k].x - C1[k].x, V[k].y - C1[k].y),
                             fmaxf(V[k].z - C1[k].z, V[k].w - C1[k].w)));
    }
#pragma unroll
    for (int off = 32; off; off >>= 1) {
        m0 = fmaxf(m0, __shfl_xor(m0, off));
        m1 = fmaxf(m1, __shfl_xor(m1, off));
    }
    if ((t & 63) == 0) {
        red[t >> 6] = m0;
        red[4 + (t >> 6)] = m1;
    }
    __syncthreads();
    m0 = fmaxf(fmaxf(red[0], red[1]), fmaxf(red[2], red[3]));
    m1 = fmaxf(fmaxf(red[4], red[5]), fmaxf(red[6], red[7]));
    float s0 = 0.f, s1 = 0.f;
#pragma unroll
    for (int k = 0; k < 4; ++k) {
        s0 += __expf((V[k].x - C0[k].x - m0) * INV_EPS);
        s0 += __expf((V[k].y - C0[k].y - m0) * INV_EPS);
        s0 += __expf((V[k].z - C0[k].z - m0) * INV_EPS);
        s0 += __expf((V[k].w - C0[k].w - m0) * INV_EPS);
        s1 += __expf((V[k].x - C1[k].x - m1) * INV_EPS);
        s1 += __expf((V[k].y - C1[k].y - m1) * INV_EPS);
        s1 += __expf((V[k].z - C1[k].z - m1) * INV_EPS);
        s1 += __expf((V[k].w - C1[k].w - m1) * INV_EPS);
    }
#pragma unroll
    for (int off = 32; off; off >>= 1) {
        s0 += __shfl_xor(s0, off);
        s1 += __shfl_xor(s1, off);
    }
    __syncthreads();  // everyone done reading maxes in red
    if ((t & 63) == 0) {
        red[t >> 6] = s0;
        red[4 + (t >> 6)] = s1;
    }
    __syncthreads();
    if (t == 0) {
        s0 = red[0] + red[1] + red[2] + red[3];
        s1 = red[4] + red[5] + red[6] + red[7];
        float un0 = target - m0 - EPS * __logf(s0);
        float un1 = target - m1 - EPS * __logf(s1);
        if (WRITE_ERR) {
            atomicAdd(errslot,
                      fabsf(un0 - mine[r0]) + fabsf(un1 - mine[r0 + 1]));
        }
        mine[r0] = un0;
        mine[r0 + 1] = un1;
    }
}

// ---------------- persistent kernel: all iterations + final ----------------
__global__ __launch_bounds__(256, 8) void sinkhorn_persist(
    const float* __restrict__ Cm, const float* __restrict__ Ct,
    float* __restrict__ ws, float* __restrict__ out, float target) {
    __shared__ float red[8];
    float* u = ws;
    float* v = ws + N;
    float* errb = ws + WS_ERR;
    const int t = threadIdx.x;
    const int b = blockIdx.x;
    const int r0 = b * RPB;

    for (int it = 0; it < MAX_ITER; ++it) {
        half_step<true>(Cm, v, u, &errb[it], r0, t, target, red);
        grid_sync(ws, b);
        half_step<false>(Ct, u, v, nullptr, r0, t, target, red);
        grid_sync(ws, b);
        // reference latches done=(err<THRESH) AFTER applying this iteration's
        // updates; subsequent iterations are frozen -> break is exact.
        if (errb[it] < THRESH) break;  // uniform: same value in every block
    }

    // ---- final: pi = exp((u_i + v_j - C_ij)/eps), cost = sum(pi*C) ----
    // Ct (aliasing out[0..N^2)) is dead from here on; pi writes may clobber it.
    float* pi = out + 1;
    float4 V[4];
    const float4* vv = (const float4*)v;
#pragma unroll
    for (int k = 0; k < 4; ++k) V[k] = vv[t + 256 * k];
    float csum = 0.f;
#pragma unroll
    for (int r = 0; r < RPB; ++r) {
        const int i = r0 + r;
        const float ui = u[i];
        const float4* crow = (const float4*)(Cm + (size_t)i * N);
        float4* prow = (float4*)(pi + (size_t)i * N);
#pragma unroll
        for (int k = 0; k < 4; ++k) {
            float4 c = crow[t + 256 * k];
            float4 p;
            p.x = __expf((ui + V[k].x - c.x) * INV_EPS);
            p.y = __expf((ui + V[k].y - c.y) * INV_EPS);
            p.z = __expf((ui + V[k].z - c.z) * INV_EPS);
            p.w = __expf((ui + V[k].w - c.w) * INV_EPS);
            prow[t + 256 * k] = p;
            csum = fmaf(p.x, c.x, csum);
            csum = fmaf(p.y, c.y, csum);
            csum = fmaf(p.z, c.z, csum);
            csum = fmaf(p.w, c.w, csum);
        }
    }
#pragma unroll
    for (int off = 32; off; off >>= 1) csum += __shfl_xor(csum, off);
    if ((t & 63) == 0) red[t >> 6] = csum;
    __syncthreads();
    if (t == 0) atomicAdd(ws + WS_COST, red[0] + red[1] + red[2] + red[3]);
    grid_sync(ws, b);
    if (b == 0 && t == 0) out[0] = ws[WS_COST];
}

extern "C" void kernel_launch(void* const* d_in, const int* in_sizes, int n_in,
                              void* d_out, int out_size, void* d_ws, size_t ws_size,
                              hipStream_t stream) {
    const float* x = (const float*)d_in[0];  // [4096,64]
    const float* y = (const float*)d_in[1];  // [4096,64]
    float* out = (float*)d_out;              // [0]=cost, [1..N*N]=pi, [1+N*N..]=C
    float* C = out + 1 + (size_t)N * N;
    float* Ct = out;  // scratch: aliases cost+pi region, dead before final writes
    float* ws = (float*)d_ws;

    init_ws<<<dim3((WS_TOTAL + 255) / 256), dim3(256), 0, stream>>>(ws);

    dim3 bgrid(64, 64);
    build_dist<<<bgrid, dim3(256), 0, stream>>>(x, y, C);   // C[i][j]
    build_dist<<<bgrid, dim3(256), 0, stream>>>(y, x, Ct);  // C^T[j][i]

    float target = EPS * logf(1.0f / (float)N + 1e-8f);  // == eps*log_mu == eps*log_nu

    sinkhorn_persist<<<dim3(NBLK), dim3(256), 0, stream>>>(C, Ct, ws, out, target);
}

// Round 3
// 4680.374 us; speedup vs baseline: 1.6753x; 1.6753x over previous
//
#include <hip/hip_runtime.h>
#include <math.h>

#define N 4096
#define DIM 64
#define MAX_ITER 50
#define EPS 0.1f
#define INV_EPS 10.0f
#define THRESH 0.1f

// persistent-kernel geometry: 1024 blocks x 256 threads (4 waves), wave-per-row.
// launch_bounds(256,4) -> VGPR<=128 -> 4 blocks/CU co-resident (grid == capacity)
#define NBLK 1024
#define NGRP 32
#define GRP_SZ (NBLK / NGRP)

// ws layout (floats). ~38 KB total.
#define WS_ERR   (2 * N)                   // err[MAX_ITER]
#define WS_COST  (2 * N + 50)              // cost accumulator
#define WS_GEN   (2 * N + 64)              // barrier root generation (own line)
#define WS_ROOT  (2 * N + 80)              // barrier root counter (own line)
#define WS_L1    (2 * N + 96)              // 32 group arrival counters, 64B stride
#define WS_GGEN  (2 * N + 96 + NGRP * 16)  // 32 per-group generation lines
#define WS_TOTAL (2 * N + 96 + 2 * NGRP * 16)

// ---------------- init: zero u, v, err, cost, barrier state ----------------
__global__ void init_ws(float* __restrict__ ws) {
    int i = blockIdx.x * 256 + threadIdx.x;
    if (i < WS_TOTAL) ws[i] = 0.0f;
}

// ---------------- build D[i][j] = sum_d (A[i][d]-B[j][d])^2 ----------------
__global__ __launch_bounds__(256) void build_dist(const float* __restrict__ A,
                                                  const float* __restrict__ B,
                                                  float* __restrict__ Dst) {
    __shared__ float As[64][68];
    __shared__ float Bs[64][68];
    const int i0 = blockIdx.y << 6, j0 = blockIdx.x << 6;
    const int t = threadIdx.x;
    const float* Ag = A + (size_t)i0 * DIM;
    const float* Bg = B + (size_t)j0 * DIM;
    for (int k = t; k < 4096; k += 256) {
        As[k >> 6][k & 63] = Ag[k];
        Bs[k >> 6][k & 63] = Bg[k];
    }
    __syncthreads();
    const int ty = t >> 4, tx = t & 15;
    float acc[4][4] = {{0.f}};
    for (int d = 0; d < DIM; d += 4) {
        float4 av[4], bv[4];
#pragma unroll
        for (int a = 0; a < 4; ++a) av[a] = *(const float4*)&As[ty + 16 * a][d];
#pragma unroll
        for (int b = 0; b < 4; ++b) bv[b] = *(const float4*)&Bs[tx + 16 * b][d];
#pragma unroll
        for (int a = 0; a < 4; ++a)
#pragma unroll
            for (int b = 0; b < 4; ++b) {
                float d0 = av[a].x - bv[b].x;
                float d1 = av[a].y - bv[b].y;
                float d2 = av[a].z - bv[b].z;
                float d3 = av[a].w - bv[b].w;
                acc[a][b] = fmaf(d0, d0, acc[a][b]);
                acc[a][b] = fmaf(d1, d1, acc[a][b]);
                acc[a][b] = fmaf(d2, d2, acc[a][b]);
                acc[a][b] = fmaf(d3, d3, acc[a][b]);
            }
    }
#pragma unroll
    for (int a = 0; a < 4; ++a) {
        int i = i0 + ty + 16 * a;
        float* drow = Dst + (size_t)i * N + j0;
#pragma unroll
        for (int b = 0; b < 4; ++b) drow[tx + 16 * b] = acc[a][b];
    }
}

// -------- grid barrier: two-level arrivals AND two-level wake ----------------
// Only NGRP last-arrivers poll the root generation; each publishes to its
// group's line, polled by <=GRP_SZ blocks. Relaxed polls + acquire fence.
__device__ __forceinline__ void grid_sync(float* ws, int b) {
    __syncthreads();  // all block lanes done with prior phase's stores
    if (threadIdx.x == 0) {
        const int g = b & (NGRP - 1);
        unsigned* gen  = (unsigned*)(ws + WS_GEN);
        unsigned* root = (unsigned*)(ws + WS_ROOT);
        unsigned* l1   = (unsigned*)(ws + WS_L1) + (size_t)g * 16;
        unsigned* ggen = (unsigned*)(ws + WS_GGEN) + (size_t)g * 16;
        unsigned old1 = __hip_atomic_fetch_add(l1, 1u, __ATOMIC_ACQ_REL,
                                               __HIP_MEMORY_SCOPE_AGENT);
        unsigned target = old1 / GRP_SZ + 1u;  // barrier index + 1
        if ((old1 % GRP_SZ) == GRP_SZ - 1u) {  // group's last arrival
            unsigned old0 = __hip_atomic_fetch_add(root, 1u, __ATOMIC_ACQ_REL,
                                                   __HIP_MEMORY_SCOPE_AGENT);
            if ((old0 % NGRP) == NGRP - 1u)    // grid's last arrival -> release
                __hip_atomic_store(gen, old0 / NGRP + 1u, __ATOMIC_RELEASE,
                                   __HIP_MEMORY_SCOPE_AGENT);
            while (__hip_atomic_load(gen, __ATOMIC_RELAXED,
                                     __HIP_MEMORY_SCOPE_AGENT) < target)
                __builtin_amdgcn_s_sleep(2);
            __builtin_amdgcn_fence(__ATOMIC_ACQUIRE, "agent");
            __hip_atomic_store(ggen, target, __ATOMIC_RELEASE,
                               __HIP_MEMORY_SCOPE_AGENT);  // wake my group
        } else {
            while (__hip_atomic_load(ggen, __ATOMIC_RELAXED,
                                     __HIP_MEMORY_SCOPE_AGENT) < target)
                __builtin_amdgcn_s_sleep(2);
            __builtin_amdgcn_fence(__ATOMIC_ACQUIRE, "agent");
        }
    }
    __syncthreads();
}

// ------- one Sinkhorn half-step, wave-per-row, SINGLE-PASS online LSE --------
// Each C element is loaded ONCE and consumed ONCE -> the register allocator
// cannot rematerialize a second read (r1/r2 failure mode). Per 16-elem chunk:
// chunk max, then one online (m,s) merge. No __syncthreads in this path.
template <bool WRITE_ERR>
__device__ __forceinline__ void half_step(const float* __restrict__ Mtx,
                                          const float* __restrict__ other,
                                          float* __restrict__ mine, int row,
                                          int lane, int wv, float target,
                                          float* red) {
    const float4* __restrict__ rowp = (const float4*)(Mtx + (size_t)row * N);
    const float4* __restrict__ vv = (const float4*)other;
    float m = -3.0e38f, s = 0.f;
#pragma unroll
    for (int g = 0; g < 4; ++g) {
        float4 c[4], w[4];
#pragma unroll
        for (int k = 0; k < 4; ++k) {
            const int f = lane + 64 * (4 * g + k);  // lane-consecutive 1KB/instr
            c[k] = rowp[f];
            w[k] = vv[f];
        }
        float d[16];
#pragma unroll
        for (int k = 0; k < 4; ++k) {
            d[4 * k + 0] = w[k].x - c[k].x;
            d[4 * k + 1] = w[k].y - c[k].y;
            d[4 * k + 2] = w[k].z - c[k].z;
            d[4 * k + 3] = w[k].w - c[k].w;
        }
        float m4[4];
#pragma unroll
        for (int k = 0; k < 4; ++k)
            m4[k] = fmaxf(fmaxf(d[4 * k], d[4 * k + 1]),
                          fmaxf(d[4 * k + 2], d[4 * k + 3]));
        float mg = fmaxf(fmaxf(m4[0], m4[1]), fmaxf(m4[2], m4[3]));
        float mn = fmaxf(m, mg);
        float ps = 0.f;
#pragma unroll
        for (int k = 0; k < 16; ++k) ps += __expf((d[k] - mn) * INV_EPS);
        s = fmaf(s, __expf((m - mn) * INV_EPS), ps);  // g==0: 0*0+ps
        m = mn;
    }
    // wave-wide online-LSE merge (6 butterfly steps, all lanes converge)
#pragma unroll
    for (int off = 32; off; off >>= 1) {
        float mo = __shfl_xor(m, off);
        float so = __shfl_xor(s, off);
        float mn = fmaxf(m, mo);
        s = fmaf(s, __expf((m - mn) * INV_EPS),
                 so * __expf((mo - mn) * INV_EPS));
        m = mn;
    }
    float un = target - m - EPS * __logf(s);
    if (lane == 0) {
        if (WRITE_ERR) red[wv] = fabsf(un - mine[row]);
        mine[row] = un;
    }
}

// ---------------- persistent kernel: all iterations + final ----------------
__global__ __launch_bounds__(256, 4) void sinkhorn_persist(
    const float* __restrict__ Cm, const float* __restrict__ Ct,
    float* __restrict__ ws, float* __restrict__ out, float target) {
    __shared__ float red[4];
    float* u = ws;
    float* v = ws + N;
    float* errb = ws + WS_ERR;
    const int t = threadIdx.x;
    const int b = blockIdx.x;
    const int lane = t & 63;
    const int wv = t >> 6;       // wave id 0..3
    const int row = b * 4 + wv;  // this wave's row

    for (int it = 0; it < MAX_ITER; ++it) {
        half_step<true>(Cm, v, u, row, lane, wv, target, red);
        __syncthreads();
        if (t == 0) atomicAdd(&errb[it], red[0] + red[1] + red[2] + red[3]);
        grid_sync(ws, b);
        half_step<false>(Ct, u, v, row, lane, wv, target, red);
        grid_sync(ws, b);
        // reference latches done AFTER applying this iteration's updates.
        if (errb[it] < THRESH) break;  // uniform across grid
    }

    // ---- final: pi = exp((u_i + v_j - C_ij)/eps), cost = sum(pi*C) ----
    // Ct (aliasing out[0..N^2)) is dead from here; pi writes may clobber it.
    {
        float* pi = out + 1;
        const float ui = u[row];
        const float4* __restrict__ crow = (const float4*)(Cm + (size_t)row * N);
        float4* __restrict__ prow = (float4*)(pi + (size_t)row * N);
        const float4* __restrict__ vv = (const float4*)v;
        float csum = 0.f;
#pragma unroll 4
        for (int k = 0; k < 16; ++k) {
            const int f = lane + 64 * k;
            float4 c = crow[f];
            float4 w = vv[f];
            float4 p;
            p.x = __expf((ui + w.x - c.x) * INV_EPS);
            p.y = __expf((ui + w.y - c.y) * INV_EPS);
            p.z = __expf((ui + w.z - c.z) * INV_EPS);
            p.w = __expf((ui + w.w - c.w) * INV_EPS);
            prow[f] = p;
            csum = fmaf(p.x, c.x, csum);
            csum = fmaf(p.y, c.y, csum);
            csum = fmaf(p.z, c.z, csum);
            csum = fmaf(p.w, c.w, csum);
        }
#pragma unroll
        for (int off = 32; off; off >>= 1) csum += __shfl_xor(csum, off);
        if (lane == 0) red[wv] = csum;
        __syncthreads();
        if (t == 0) atomicAdd(ws + WS_COST, red[0] + red[1] + red[2] + red[3]);
    }
    grid_sync(ws, b);
    if (b == 0 && t == 0) out[0] = ws[WS_COST];
}

extern "C" void kernel_launch(void* const* d_in, const int* in_sizes, int n_in,
                              void* d_out, int out_size, void* d_ws, size_t ws_size,
                              hipStream_t stream) {
    const float* x = (const float*)d_in[0];  // [4096,64]
    const float* y = (const float*)d_in[1];  // [4096,64]
    float* out = (float*)d_out;              // [0]=cost, [1..N*N]=pi, [1+N*N..]=C
    float* C = out + 1 + (size_t)N * N;
    float* Ct = out;  // scratch: aliases cost+pi region, dead before final writes
    float* ws = (float*)d_ws;

    init_ws<<<dim3((WS_TOTAL + 255) / 256), dim3(256), 0, stream>>>(ws);

    dim3 bgrid(64, 64);
    build_dist<<<bgrid, dim3(256), 0, stream>>>(x, y, C);   // C[i][j]
    build_dist<<<bgrid, dim3(256), 0, stream>>>(y, x, Ct);  // C^T[j][i]

    float target = EPS * logf(1.0f / (float)N + 1e-8f);  // == eps*log_mu == eps*log_nu

    sinkhorn_persist<<<dim3(NBLK), dim3(256), 0, stream>>>(C, Ct, ws, out, target);
}

// Round 4
// 1430.354 us; speedup vs baseline: 5.4818x; 3.2722x over previous
//
#include <hip/hip_runtime.h>
#include <math.h>

#define N 4096
#define DIM 64
#define MAX_ITER 50
#define EPS 0.1f
#define INV_EPS 10.0f
#define THRESH 0.1f

// 256 blocks x 1024 threads (16 waves), 16 rows/block, 1 block/CU guaranteed.
#define NBLK 256
#define TPB 1024
#define WAVES 16
#define NREP 16  // wake replicas

// ws layout (floats). All cross-block data accessed ONLY via relaxed
// agent-scope atomics (sc0/sc1: L2-bypass, coherent at L3, NO cache-wide
// invalidate/writeback ops -> C/Ct stay L2-resident across phases).
#define WS_U 0
#define WS_V N
#define WS_FLAGS (2 * N)                  // 256 x (u32 gen, f32 val) 8B pairs
#define WS_GGEN (2 * N + 2 * NBLK)        // 16 replicas x 16-word stride
#define WS_TOTAL (2 * N + 2 * NBLK + NREP * 16)

// ---------------- init: zero u, v, flags, replicas ----------------
__global__ void init_ws(float* __restrict__ ws) {
    int i = blockIdx.x * 256 + threadIdx.x;
    if (i < WS_TOTAL) ws[i] = 0.0f;
}

// ---------------- build D[i][j] = sum_d (A[i][d]-B[j][d])^2 ----------------
__global__ __launch_bounds__(256) void build_dist(const float* __restrict__ A,
                                                  const float* __restrict__ B,
                                                  float* __restrict__ Dst) {
    __shared__ float As[64][68];
    __shared__ float Bs[64][68];
    const int i0 = blockIdx.y << 6, j0 = blockIdx.x << 6;
    const int t = threadIdx.x;
    const float* Ag = A + (size_t)i0 * DIM;
    const float* Bg = B + (size_t)j0 * DIM;
    for (int k = t; k < 4096; k += 256) {
        As[k >> 6][k & 63] = Ag[k];
        Bs[k >> 6][k & 63] = Bg[k];
    }
    __syncthreads();
    const int ty = t >> 4, tx = t & 15;
    float acc[4][4] = {{0.f}};
    for (int d = 0; d < DIM; d += 4) {
        float4 av[4], bv[4];
#pragma unroll
        for (int a = 0; a < 4; ++a) av[a] = *(const float4*)&As[ty + 16 * a][d];
#pragma unroll
        for (int b = 0; b < 4; ++b) bv[b] = *(const float4*)&Bs[tx + 16 * b][d];
#pragma unroll
        for (int a = 0; a < 4; ++a)
#pragma unroll
            for (int b = 0; b < 4; ++b) {
                float d0 = av[a].x - bv[b].x;
                float d1 = av[a].y - bv[b].y;
                float d2 = av[a].z - bv[b].z;
                float d3 = av[a].w - bv[b].w;
                acc[a][b] = fmaf(d0, d0, acc[a][b]);
                acc[a][b] = fmaf(d1, d1, acc[a][b]);
                acc[a][b] = fmaf(d2, d2, acc[a][b]);
                acc[a][b] = fmaf(d3, d3, acc[a][b]);
            }
    }
#pragma unroll
    for (int a = 0; a < 4; ++a) {
        int i = i0 + ty + 16 * a;
        float* drow = Dst + (size_t)i * N + j0;
#pragma unroll
        for (int b = 0; b < 4; ++b) drow[tx + 16 * b] = acc[a][b];
    }
}

// -------- grid barrier: flag-array + dedicated scanner, payload-carrying -----
// Arrive: one 8B relaxed-agent store (gen, blockPartial) per block -> no RMWs.
// Block 0 wave 0 scans all 256 flags (4 loads/lane), wave-reduces the payload
// sum, publishes (gen, sum) to 16 replicas. Others poll their replica.
// Ordering: entry __syncthreads drains every lane's u/v stores (vmcnt 0)
// before the flag store is issued; readers access u/v with sc1 loads (L3 is
// the single serialization point) -> no acquire/release cache ops needed.
__device__ __forceinline__ float grid_sync(float* ws, int b, int t, unsigned G,
                                           const float* red2, float* bcast,
                                           bool wake) {
    __syncthreads();  // red2 complete; all prior sc1 stores retired
    if (t == 0) {
        float s = 0.f;
#pragma unroll
        for (int i = 0; i < WAVES; ++i) s += red2[i];
        unsigned long long pk = (unsigned long long)G |
                                ((unsigned long long)__float_as_uint(s) << 32);
        __hip_atomic_store((unsigned long long*)(ws + WS_FLAGS) + b, pk,
                           __ATOMIC_RELAXED, __HIP_MEMORY_SCOPE_AGENT);
    }
    if (b == 0 && t < 64) {  // scanner wave
        unsigned long long* fl = (unsigned long long*)(ws + WS_FLAGS);
        float sum;
        for (;;) {
            bool ok = true;
            sum = 0.f;
#pragma unroll
            for (int j = 0; j < NBLK / 64; ++j) {
                unsigned long long q =
                    __hip_atomic_load(fl + (t * (NBLK / 64) + j),
                                      __ATOMIC_RELAXED, __HIP_MEMORY_SCOPE_AGENT);
                ok = ok && ((unsigned)q >= G);
                sum += __uint_as_float((unsigned)(q >> 32));
            }
            if (__all(ok)) break;
            __builtin_amdgcn_s_sleep(1);
        }
#pragma unroll
        for (int off = 32; off; off >>= 1) sum += __shfl_xor(sum, off);
        if (wake && t < NREP) {
            unsigned long long pk =
                (unsigned long long)G |
                ((unsigned long long)__float_as_uint(sum) << 32);
            __hip_atomic_store((unsigned long long*)(ws + WS_GGEN) + t * 8, pk,
                               __ATOMIC_RELAXED, __HIP_MEMORY_SCOPE_AGENT);
        }
        if (t == 0) *bcast = sum;
    } else if (t == 0 && wake) {  // b != 0
        unsigned long long* gp =
            (unsigned long long*)(ws + WS_GGEN) + (b & (NREP - 1)) * 8;
        unsigned long long q;
        for (;;) {
            q = __hip_atomic_load(gp, __ATOMIC_RELAXED, __HIP_MEMORY_SCOPE_AGENT);
            if ((unsigned)q >= G) break;
            __builtin_amdgcn_s_sleep(8);
        }
        *bcast = __uint_as_float((unsigned)(q >> 32));
    }
    __syncthreads();
    return *bcast;  // valid when wake (all blocks) or b==0
}

// ---------------- stage a 4096-float vector into LDS via sc1 loads -----------
__device__ __forceinline__ void stage(const float* __restrict__ src,
                                      float* __restrict__ sv, int t) {
    const unsigned long long* s8 = (const unsigned long long*)src;
#pragma unroll
    for (int i = 0; i < 2; ++i) {
        int idx = t + TPB * i;  // 0..2047
        unsigned long long q = __hip_atomic_load(s8 + idx, __ATOMIC_RELAXED,
                                                 __HIP_MEMORY_SCOPE_AGENT);
        sv[2 * idx] = __uint_as_float((unsigned)q);
        sv[2 * idx + 1] = __uint_as_float((unsigned)(q >> 32));
    }
}

// ------- one Sinkhorn half-step, wave-per-row, single-pass online LSE --------
// C row: plain cached float4 loads (L2 serves it; never invalidated).
// src vector: LDS. dst scalar: sc1 atomic store.
template <bool WERR>
__device__ __forceinline__ void phase(const float* __restrict__ Mtx,
                                      const float* __restrict__ sv,
                                      float* __restrict__ dst, int row,
                                      int lane, int wv, float target,
                                      float* red2) {
    const float4* __restrict__ rowp = (const float4*)(Mtx + (size_t)row * N);
    const float4* __restrict__ svv = (const float4*)sv;
    float old = 0.f;
    if (WERR && lane == 0)  // hoisted: latency overlaps the streaming loop
        old = __hip_atomic_load(&dst[row], __ATOMIC_RELAXED,
                                __HIP_MEMORY_SCOPE_AGENT);
    float m = -3.0e38f, s = 0.f;
#pragma unroll
    for (int g = 0; g < 4; ++g) {
        float4 c[4], w[4];
#pragma unroll
        for (int k = 0; k < 4; ++k) {
            const int f = lane + 64 * (4 * g + k);
            c[k] = rowp[f];
            w[k] = svv[f];
        }
        float d[16];
#pragma unroll
        for (int k = 0; k < 4; ++k) {
            d[4 * k + 0] = w[k].x - c[k].x;
            d[4 * k + 1] = w[k].y - c[k].y;
            d[4 * k + 2] = w[k].z - c[k].z;
            d[4 * k + 3] = w[k].w - c[k].w;
        }
        float m4[4];
#pragma unroll
        for (int k = 0; k < 4; ++k)
            m4[k] = fmaxf(fmaxf(d[4 * k], d[4 * k + 1]),
                          fmaxf(d[4 * k + 2], d[4 * k + 3]));
        float mg = fmaxf(fmaxf(m4[0], m4[1]), fmaxf(m4[2], m4[3]));
        float mn = fmaxf(m, mg);
        float ps = 0.f;
#pragma unroll
        for (int k = 0; k < 16; ++k) ps += __expf((d[k] - mn) * INV_EPS);
        s = fmaf(s, __expf((m - mn) * INV_EPS), ps);
        m = mn;
    }
#pragma unroll
    for (int off = 32; off; off >>= 1) {
        float mo = __shfl_xor(m, off);
        float so = __shfl_xor(s, off);
        float mn = fmaxf(m, mo);
        s = fmaf(s, __expf((m - mn) * INV_EPS), so * __expf((mo - mn) * INV_EPS));
        m = mn;
    }
    float un = target - m - EPS * __logf(s);
    if (lane == 0) {
        red2[wv] = WERR ? fabsf(un - old) : 0.f;
        __hip_atomic_store(&dst[row], un, __ATOMIC_RELAXED,
                           __HIP_MEMORY_SCOPE_AGENT);
    }
}

// ---------------- persistent kernel: all iterations + final ----------------
__global__ __launch_bounds__(TPB, 4) void sinkhorn_persist(
    const float* __restrict__ Cm, const float* __restrict__ Ct,
    float* __restrict__ ws, float* __restrict__ out, float target) {
    __shared__ float sv[N];      // 16 KB staged vector
    __shared__ float red2[WAVES];
    __shared__ float bcast;
    float* u = ws + WS_U;
    float* v = ws + WS_V;
    const int t = threadIdx.x;
    const int b = blockIdx.x;
    const int lane = t & 63, wv = t >> 6;
    const int row = (b << 4) + wv;
    unsigned G = 1;
    float errv = 1e30f;

    for (int it = 0; it < MAX_ITER; ++it) {
        stage(v, sv, t);
        __syncthreads();
        phase<true>(Cm, sv, u, row, lane, wv, target, red2);
        errv = grid_sync(ws, b, t, G++, red2, &bcast, true);  // total err
        stage(u, sv, t);
        __syncthreads();
        phase<false>(Ct, sv, v, row, lane, wv, target, red2);
        grid_sync(ws, b, t, G++, red2, &bcast, true);
        // reference latches done AFTER applying this iteration's updates.
        if (errv < THRESH) break;  // uniform: same published value everywhere
    }

    // ---- final: pi = exp((u_i + v_j - C_ij)/eps), cost = sum(pi*C) ----
    // Ct (aliasing out[0..N^2)) is dead from here; pi writes may clobber it.
    stage(v, sv, t);
    __syncthreads();
    {
        float* pi = out + 1;
        const float ui = __hip_atomic_load(&u[row], __ATOMIC_RELAXED,
                                           __HIP_MEMORY_SCOPE_AGENT);
        const float4* __restrict__ crow = (const float4*)(Cm + (size_t)row * N);
        float4* __restrict__ prow = (float4*)(pi + (size_t)row * N);
        const float4* __restrict__ svv = (const float4*)sv;
        float csum = 0.f;
#pragma unroll 4
        for (int k = 0; k < 16; ++k) {
            const int f = lane + 64 * k;
            float4 c = crow[f];
            float4 w = svv[f];
            float4 p;
            p.x = __expf((ui + w.x - c.x) * INV_EPS);
            p.y = __expf((ui + w.y - c.y) * INV_EPS);
            p.z = __expf((ui + w.z - c.z) * INV_EPS);
            p.w = __expf((ui + w.w - c.w) * INV_EPS);
            prow[f] = p;
            csum = fmaf(p.x, c.x, csum);
            csum = fmaf(p.y, c.y, csum);
            csum = fmaf(p.z, c.z, csum);
            csum = fmaf(p.w, c.w, csum);
        }
#pragma unroll
        for (int off = 32; off; off >>= 1) csum += __shfl_xor(csum, off);
        if (lane == 0) red2[wv] = csum;
    }
    // cost rides the final barrier payload; only the scanner needs the total.
    float ctot = grid_sync(ws, b, t, G++, red2, &bcast, false);
    if (b == 0 && t == 0) out[0] = ctot;
}

extern "C" void kernel_launch(void* const* d_in, const int* in_sizes, int n_in,
                              void* d_out, int out_size, void* d_ws, size_t ws_size,
                              hipStream_t stream) {
    const float* x = (const float*)d_in[0];  // [4096,64]
    const float* y = (const float*)d_in[1];  // [4096,64]
    float* out = (float*)d_out;              // [0]=cost, [1..N*N]=pi, [1+N*N..]=C
    float* C = out + 1 + (size_t)N * N;
    float* Ct = out;  // scratch: aliases cost+pi region, dead before final writes
    float* ws = (float*)d_ws;

    init_ws<<<dim3((WS_TOTAL + 255) / 256), dim3(256), 0, stream>>>(ws);

    dim3 bgrid(64, 64);
    build_dist<<<bgrid, dim3(256), 0, stream>>>(x, y, C);   // C[i][j]
    build_dist<<<bgrid, dim3(256), 0, stream>>>(y, x, Ct);  // C^T[j][i]

    float target = EPS * logf(1.0f / (float)N + 1e-8f);  // == eps*log_mu == eps*log_nu

    sinkhorn_persist<<<dim3(NBLK), dim3(TPB), 0, stream>>>(C, Ct, ws, out, target);
}